// Round 4
// baseline (597.576 us; speedup 1.0000x reference)
//
#include <hip/hip_runtime.h>
#include <math.h>

// x: [B=2, C=1, D=64, H=256, W=256] fp32
// out: [B=2, 16, D=64, H=256, W=256] fp32
//   even channels = sobel magnitude of x (per 2D HxW slice, zero-padded SAME)
//   odd  channels = x
//
// v4: fill-mimicking decomposition. One block owns a 64-row quarter of ONE
// output channel-slice and writes it as a single linear 64 KB sweep
// (the ~6.2 TB/s fill pattern). Odd channels: pure streaming copy. Even
// channels: sobel recomputed per copy (chip-wide compute cost ~10 us, free).
// blockIdx layout puts all 16 channel copies of a (slice, quarter) on the
// same XCD (blockIdx stride 256 == 0 mod 8), so input chunks are read once
// per XCD-L2 and reused 16x; HBM reads stay ~33.5 MB. Writes nontemporal.

#define Hh 256
#define Ww 256
#define CH_ELEMS (Hh * Ww)   // elements per channel-slice

typedef float f32x4 __attribute__((ext_vector_type(4)));

__global__ __launch_bounds__(256) void sobel_cat_kernel(
    const float* __restrict__ in, float* __restrict__ out) {
  const int bid = blockIdx.x;
  const int m = bid >> 2;              // channel-slice index 0..2047
  const int q = bid & 3;               // quarter (64 rows) 0..3
  const int c = (m >> 6) & 15;         // channel
  const int n = ((m >> 10) << 6) | (m & 63);  // input slice b*64+d

  const int w4   = threadIdx.x & 63;   // lane
  const int rsub = threadIdx.x >> 6;   // wave id 0..3 (uniform per wave)
  const int w    = w4 << 2;

  const float* src = in + (size_t)n * CH_ELEMS;
  float* dst = out + (size_t)m * CH_ELEMS + (size_t)(q << 6) * Ww;

  if (c & 1) {
    // Passthrough channel: pure streaming 64 KB copy.
    #pragma unroll 4
    for (int it = 0; it < 16; ++it) {
      const int r  = (it << 2) + rsub;        // row within quarter, 0..63
      const int lr = (q << 6) + r;            // row within slice
      f32x4 v = *(const f32x4*)(src + lr * Ww + w);
      __builtin_nontemporal_store(v, (f32x4*)(dst + r * Ww + w));
    }
  } else {
    // Sobel channel: recompute sobel for this quarter, write linearly.
    #pragma unroll 2
    for (int it = 0; it < 16; ++it) {
      const int r  = (it << 2) + rsub;
      const int lr = (q << 6) + r;

      float rm[6], r0[6], rp[6];
      {
        const float* rowp = src + lr * Ww;
        f32x4 cc = *(const f32x4*)(rowp + w);
        r0[1] = cc.x; r0[2] = cc.y; r0[3] = cc.z; r0[4] = cc.w;
        r0[0] = (w4 > 0)  ? rowp[w - 1] : 0.f;
        r0[5] = (w4 < 63) ? rowp[w + 4] : 0.f;
      }
      if (lr > 0) {  // wave-uniform branch
        const float* rowp = src + (lr - 1) * Ww;
        f32x4 cc = *(const f32x4*)(rowp + w);
        rm[1] = cc.x; rm[2] = cc.y; rm[3] = cc.z; rm[4] = cc.w;
        rm[0] = (w4 > 0)  ? rowp[w - 1] : 0.f;
        rm[5] = (w4 < 63) ? rowp[w + 4] : 0.f;
      } else {
        #pragma unroll
        for (int i = 0; i < 6; ++i) rm[i] = 0.f;
      }
      if (lr < Hh - 1) {  // wave-uniform branch
        const float* rowp = src + (lr + 1) * Ww;
        f32x4 cc = *(const f32x4*)(rowp + w);
        rp[1] = cc.x; rp[2] = cc.y; rp[3] = cc.z; rp[4] = cc.w;
        rp[0] = (w4 > 0)  ? rowp[w - 1] : 0.f;
        rp[5] = (w4 < 63) ? rowp[w + 4] : 0.f;
      } else {
        #pragma unroll
        for (int i = 0; i < 6; ++i) rp[i] = 0.f;
      }

      float sv[4];
      #pragma unroll
      for (int i = 0; i < 4; ++i) {
        float gx = (rm[i + 2] - rm[i]) + 2.f * (r0[i + 2] - r0[i]) + (rp[i + 2] - rp[i]);
        float gy = (rp[i] - rm[i]) + 2.f * (rp[i + 1] - rm[i + 1]) + (rp[i + 2] - rm[i + 2]);
        sv[i] = sqrtf(gx * gx + gy * gy);
      }
      f32x4 s;
      s.x = sv[0]; s.y = sv[1]; s.z = sv[2]; s.w = sv[3];
      __builtin_nontemporal_store(s, (f32x4*)(dst + r * Ww + w));
    }
  }
}

extern "C" void kernel_launch(void* const* d_in, const int* in_sizes, int n_in,
                              void* d_out, int out_size, void* d_ws, size_t ws_size,
                              hipStream_t stream) {
  const float* x = (const float*)d_in[0];
  float* out = (float*)d_out;
  // 2048 channel-slices x 4 quarters = 8192 blocks of 256 threads
  const int grid = 8192;
  const int block = 256;
  sobel_cat_kernel<<<grid, block, 0, stream>>>(x, out);
}

// Round 5
// 550.687 us; speedup vs baseline: 1.0851x; 1.0851x over previous
//
#include <hip/hip_runtime.h>
#include <math.h>

// x: [B=2, C=1, D=64, H=256, W=256] fp32
// out: [B=2, 16, D=64, H=256, W=256] fp32
//   even channels = sobel magnitude of x (per 2D HxW slice, zero-padded SAME)
//   odd  channels = x
//
// v5: one block = one 256-KiB output channel-slice chunk (2048 blocks = full
// device). Each of the 4 waves owns a 64-row strip, swept linearly with a
// rolling 3-row register window (1 new row load per row produced; col halos
// via __shfl instead of unaligned loads). bid&7 groups all 16 channel copies
// of a 16-slice group on one XCD: its 4 MiB input working set == the 4 MiB
// XCD L2, and nt output stores bypass L2 so they never evict it. All branches
// wave-uniform. Writes are long per-wave linear streams (fill-like).

#define CH_ELEMS 65536   // 256*256
#define Ww 256

typedef float f32x4 __attribute__((ext_vector_type(4)));

__device__ __forceinline__ void edges(f32x4 v, int lane, float& L, float& R) {
  float l = __shfl_up(v.w, 1);    // lane-1's last element  == col w-1
  float r = __shfl_down(v.x, 1);  // lane+1's first element == col w+4
  L = (lane == 0)  ? 0.f : l;     // image left edge -> zero pad
  R = (lane == 63) ? 0.f : r;     // image right edge -> zero pad
}

__global__ __launch_bounds__(256) void sobel_cat_kernel(
    const float* __restrict__ in, float* __restrict__ out) {
  const int bid = blockIdx.x;
  const int g  = bid & 7;      // XCD group (assumes round-robin bid%8)
  const int j  = bid >> 3;     // 0..255 within group
  const int c  = j >> 4;       // channel 0..15
  const int nl = j & 15;       // slice within group
  const int n  = (g << 4) + nl;  // global slice 0..127 (= b*64+d)
  const int b  = n >> 6;
  const int d  = n & 63;

  const int lane = threadIdx.x & 63;
  const int wv   = threadIdx.x >> 6;   // wave 0..3
  const int w    = lane << 2;
  const int row0 = wv << 6;            // first row of this wave's strip

  const float* src = in + (size_t)n * CH_ELEMS;
  float* dst = out + ((size_t)((b * 16 + c) * 64 + d)) * CH_ELEMS;

  if (c & 1) {
    // Passthrough channel: linear strip copy (1 KiB load + 1 KiB nt store per
    // wave-row).
    #pragma unroll 4
    for (int i = 0; i < 64; ++i) {
      const int rr = row0 + i;
      f32x4 v = *(const f32x4*)(src + rr * Ww + w);
      __builtin_nontemporal_store(v, (f32x4*)(dst + rr * Ww + w));
    }
  } else {
    // Sobel channel: rolling window pm (row rr-1), pc (row rr), pn (row rr+1).
    const f32x4 zero = {0.f, 0.f, 0.f, 0.f};
    f32x4 pm, pc;
    float pmL, pmR, pcL, pcR;
    pm = (row0 > 0) ? *(const f32x4*)(src + (row0 - 1) * Ww + w) : zero;
    edges(pm, lane, pmL, pmR);
    pc = *(const f32x4*)(src + row0 * Ww + w);
    edges(pc, lane, pcL, pcR);

    #pragma unroll 2
    for (int i = 0; i < 64; ++i) {
      const int rr = row0 + i;
      f32x4 pn = (rr + 1 < 256) ? *(const f32x4*)(src + (rr + 1) * Ww + w)
                                : zero;  // wave-uniform condition
      float pnL, pnR;
      edges(pn, lane, pnL, pnR);

      const float rm[6] = {pmL, pm.x, pm.y, pm.z, pm.w, pmR};
      const float r0[6] = {pcL, pc.x, pc.y, pc.z, pc.w, pcR};
      const float rp[6] = {pnL, pn.x, pn.y, pn.z, pn.w, pnR};

      float sv[4];
      #pragma unroll
      for (int k = 0; k < 4; ++k) {
        float gx = (rm[k + 2] - rm[k]) + 2.f * (r0[k + 2] - r0[k]) + (rp[k + 2] - rp[k]);
        float gy = (rp[k] - rm[k]) + 2.f * (rp[k + 1] - rm[k + 1]) + (rp[k + 2] - rm[k + 2]);
        sv[k] = sqrtf(gx * gx + gy * gy);
      }
      f32x4 s;
      s.x = sv[0]; s.y = sv[1]; s.z = sv[2]; s.w = sv[3];
      __builtin_nontemporal_store(s, (f32x4*)(dst + rr * Ww + w));

      pm = pc; pmL = pcL; pmR = pcR;
      pc = pn; pcL = pnL; pcR = pnR;
    }
  }
}

extern "C" void kernel_launch(void* const* d_in, const int* in_sizes, int n_in,
                              void* d_out, int out_size, void* d_ws, size_t ws_size,
                              hipStream_t stream) {
  const float* x = (const float*)d_in[0];
  float* out = (float*)d_out;
  // 8 XCD groups x 16 channels x 16 slices = 2048 blocks of 256 threads
  // (= 524288 threads = exactly one full-device resident wavefront set)
  sobel_cat_kernel<<<2048, 256, 0, stream>>>(x, out);
}